// Round 3
// baseline (197.139 us; speedup 1.0000x reference)
//
#include <hip/hip_runtime.h>
#include <hip/hip_bf16.h>

#define EPS 1e-3f
#define NPIX  50176   // 16*56*56
#define NOPIX 12544   // 16*28*28

// ws float offsets
#define OFF_S2   0        // [32][4]  s2
#define OFF_T2   128      // [32][4]  t2
#define OFF_T3   256      // [128]
#define OFF_BSUM 384      // [256]
#define OFF_W3S  640      // [128 k][36 = 9kk x 4ci] pre-scaled by s3
#define OFF_T3P  5248     // [32 g][128 c]  t' = bn1 shift in relu(x+t') form
#define OFF_WAF  9344     // A-frag table: [32 g][4 kk][64 lane][8 bf16] (32768 floats)
#define OFF_U    42112    // [32 g][50176 px] ushort4 (bf16, g-planar)
#define OFF_V    3253376  // [12544 opx][128 k] f32 conv3 output (post BN3+ReLU)

typedef __attribute__((ext_vector_type(8))) short short8v;
typedef __attribute__((ext_vector_type(4))) float float4v;

__device__ __forceinline__ unsigned short f2bf(float f) {
    unsigned u = __float_as_uint(f);
    return (unsigned short)((u + 0x7fffu + ((u >> 16) & 1u)) >> 16);
}
__device__ __forceinline__ float bf2f(unsigned short s) {
    return __uint_as_float(((unsigned)s) << 16);
}
__device__ __forceinline__ unsigned pk2bf(float lo, float hi) {
    __hip_bfloat162 p = __float22bfloat162_rn(make_float2(lo, hi)); // RNE, lo in bits[15:0]
    union { __hip_bfloat162 h; unsigned u; } c; c.h = p;
    return c.u;
}

__global__ __launch_bounds__(256)
void prep_kernel(const float* __restrict__ g1, const float* __restrict__ be1,
                 const float* __restrict__ m1, const float* __restrict__ v1,
                 const float* __restrict__ W1, const float* __restrict__ b1,
                 const float* __restrict__ g2, const float* __restrict__ be2,
                 const float* __restrict__ m2, const float* __restrict__ v2,
                 const float* __restrict__ W3, const float* __restrict__ b3,
                 const float* __restrict__ g3, const float* __restrict__ be3,
                 const float* __restrict__ m3, const float* __restrict__ v3,
                 const float* __restrict__ b2, float* __restrict__ ws) {
    int gid = blockIdx.x * 256 + threadIdx.x;
    int stride = gridDim.x * 256;
    // t' table [g][c]: relu(bn1(x)) = s1 * relu(x + t'), t' = be1/s1 - m1
    for (int i = gid; i < 4096; i += stride) {
        float s = g1[i] * rsqrtf(v1[i] + EPS);
        ws[OFF_T3P + i] = be1[i] / s - m1[i];
    }
    // W' A-fragment table (bf16): lane l holds A[m=l&15][k=(l>>4)*8+j], m=f (<4), k=c within kk-slice
    {
        unsigned short* wsu = (unsigned short*)(ws + OFF_WAF);
        for (int i = gid; i < 65536; i += stride) {
            int j    = i & 7;
            int lane = (i >> 3) & 63;
            int kk   = (i >> 9) & 3;
            int g    = i >> 11;
            int f    = lane & 15;
            int c    = kk*32 + (lane >> 4)*8 + j;
            unsigned short v = 0;
            if (f < 4) {
                float s = g1[g*128 + c] * rsqrtf(v1[g*128 + c] + EPS);
                v = f2bf(s * W1[g*512 + c*4 + f]);
            }
            wsu[i] = v;
        }
    }
    // W3 re-laid [k][kk*4+ci], pre-scaled by s3  (k = g*4+f)
    for (int i = gid; i < 4608; i += stride) {
        int k = i / 36, j = i - k*36;
        int kk = j >> 2, ci = j & 3;
        int g = k >> 2, f = k & 3;
        float s3 = g3[k] * rsqrtf(v3[k] + EPS);
        ws[OFF_W3S + i] = W3[g*144 + kk*16 + ci*4 + f] * s3;
    }
    if (gid < 128) {
        float s2 = g2[gid] * rsqrtf(v2[gid] + EPS);
        ws[OFF_S2 + gid] = s2;
        ws[OFF_T2 + gid] = be2[gid] + (b1[gid] - m2[gid]) * s2;
        float s3 = g3[gid] * rsqrtf(v3[gid] + EPS);
        ws[OFF_T3 + gid] = be3[gid] + (b3[gid] - m3[gid]) * s3;
    } else if (gid >= 256 && gid < 512) {
        int co = gid - 256;
        float acc = 0.f;
        for (int g = 0; g < 32; ++g) acc += b2[g*256 + co];
        ws[OFF_BSUM + co] = acc;
    }
}

// Stage 1 (MFMA): grid = 784 64-px tiles; block 256 = 4 waves; wave owns 8 g.
// D = W'^T (M=f) x z^T (N=px) via mfma_f32_16x16x32_bf16, K=128 in 4 slices.
// C/D layout puts all 4 f of one px in one lane's regs -> direct ushort4 store.
__global__ __launch_bounds__(256)
void stage1_kernel(const float* __restrict__ x,
                   const float* __restrict__ tabs,   // ws
                   float* __restrict__ uout) {       // ws + OFF_U
    __shared__ float4 xs4[2048];   // 32 KB: 64 px x 32 float4, XOR-swizzled
    int tid = threadIdx.x;
    int tile = blockIdx.x;

    const float4* xg = (const float4*)x + (size_t)tile * 2048;
    for (int i = tid; i < 2048; i += 256) {
        int p = i >> 5, c4 = i & 31;
        xs4[p*32 + (c4 ^ (p & 31))] = xg[i];
    }
    __syncthreads();

    int lane = tid & 63;
    int g0 = __builtin_amdgcn_readfirstlane((tid >> 6) * 8);
    int l15 = lane & 15;
    int lq  = lane >> 4;           // k-chunk: k = lq*8 + j

    const uint4* wafp = (const uint4*)(tabs + OFF_WAF);
    uint2* Uo = (uint2*)uout;

    #pragma unroll 1
    for (int t = 0; t < 4; ++t) {
        int pxl = t*16 + l15;      // B-frag: n = px = l15
        // x fragment: 8 floats per kk-slice (c = kk*32 + lq*8 + j)
        float4 xf[8];
        #pragma unroll
        for (int kk = 0; kk < 4; ++kk) {
            xf[kk*2]   = xs4[pxl*32 + ((kk*8 + lq*2    ) ^ (pxl & 31))];
            xf[kk*2+1] = xs4[pxl*32 + ((kk*8 + lq*2 + 1) ^ (pxl & 31))];
        }
        #pragma unroll 1
        for (int gi = 0; gi < 8; ++gi) {
            int g = g0 + gi;
            union { uint4 u; short8v s; } af[4];
            #pragma unroll
            for (int kk = 0; kk < 4; ++kk)
                af[kk].u = wafp[(g*4 + kk)*64 + lane];
            float4v acc = {0.f, 0.f, 0.f, 0.f};
            #pragma unroll
            for (int kk = 0; kk < 4; ++kk) {
                const float4* tp = (const float4*)(tabs + OFF_T3P + g*128 + kk*32 + lq*8);
                float4 ta = tp[0], tb = tp[1];
                float4 xa = xf[kk*2], xb = xf[kk*2+1];
                float z0 = fmaxf(xa.x + ta.x, 0.f);
                float z1 = fmaxf(xa.y + ta.y, 0.f);
                float z2 = fmaxf(xa.z + ta.z, 0.f);
                float z3 = fmaxf(xa.w + ta.w, 0.f);
                float z4 = fmaxf(xb.x + tb.x, 0.f);
                float z5 = fmaxf(xb.y + tb.y, 0.f);
                float z6 = fmaxf(xb.z + tb.z, 0.f);
                float z7 = fmaxf(xb.w + tb.w, 0.f);
                union { unsigned u[4]; short8v s; } zz;
                zz.u[0] = pk2bf(z0, z1);
                zz.u[1] = pk2bf(z2, z3);
                zz.u[2] = pk2bf(z4, z5);
                zz.u[3] = pk2bf(z6, z7);
                acc = __builtin_amdgcn_mfma_f32_16x16x32_bf16(af[kk].s, zz.s, acc, 0, 0, 0);
            }
            // epilogue: lane<16 holds px=pxl's f0..3 in acc[0..3]
            const float* s2p = tabs + OFF_S2 + g*4;
            const float* t2p = tabs + OFF_T2 + g*4;
            float o0 = fmaxf(fmaf(acc[0], s2p[0], t2p[0]), 0.f);
            float o1 = fmaxf(fmaf(acc[1], s2p[1], t2p[1]), 0.f);
            float o2 = fmaxf(fmaf(acc[2], s2p[2], t2p[2]), 0.f);
            float o3 = fmaxf(fmaf(acc[3], s2p[3], t2p[3]), 0.f);
            uint2 val;
            val.x = pk2bf(o0, o1);
            val.y = pk2bf(o2, o3);
            if (lane < 16)
                Uo[(size_t)g * NPIX + tile*64 + t*16 + lane] = val;
        }
    }
}

// Stage 2a: 3x3 stride-2 conv. Block = quarter-row (7 opx), 256 thr, grid 1792.
__global__ __launch_bounds__(256)
void stage2a_kernel(const float* __restrict__ tabs,   // ws
                    const float* __restrict__ U,      // ws + OFF_U (bf16)
                    float* __restrict__ V) {          // ws + OFF_V
    __shared__ ushort4 patch[3*16*32];   // [r][c][g ^ c]   12288 B

    int tid = threadIdx.x;
    int row = blockIdx.x >> 2;           // b*28 + oh
    int q   = blockIdx.x & 3;            // quarter: opx = q*7 .. q*7+6
    int b = row / 28, oh = row - b*28;

    // ---- stage U patch: rows ih = 2oh-1..2oh+1, cols ic = 14q-1 .. 14q+13 ----
    {
        const ushort4* Uu = (const ushort4*)U;
        #pragma unroll 1
        for (int i = tid; i < 1440; i += 256) {
            int g = i / 45;
            int rem = i - g*45;
            int r = rem / 15;            // 0..2
            int c = rem - r*15;          // 0..14
            int ih = 2*oh - 1 + r;
            int ic = 14*q - 1 + c;
            ushort4 v = make_ushort4(0, 0, 0, 0);
            if (ih >= 0 && ic >= 0)
                v = Uu[(size_t)g * NPIX + (b*56 + ih)*56 + ic];
            patch[(r*16 + c)*32 + (g ^ c)] = v;
        }
    }

    // weights into VGPRs: 9 float4 per thread (L2-hot table)
    int k = tid & 127, s = tid >> 7;     // s in {0,1}
    int g = k >> 2;
    float4 w[9];
    {
        const float4* wk = (const float4*)(tabs + OFF_W3S + k*36);
        #pragma unroll
        for (int kk = 0; kk < 9; ++kk) w[kk] = wk[kk];
    }
    float t3 = tabs[OFF_T3 + k];
    __syncthreads();

    // ---- conv: opx_l = s + 2j (parity split), each ushort4 read broadcast x4 f ----
    #pragma unroll
    for (int j = 0; j < 4; ++j) {
        int opx_l = s + 2*j;
        if (opx_l > 6) break;
        float acc = 0.f;
        #pragma unroll
        for (int kh = 0; kh < 3; ++kh) {
            #pragma unroll
            for (int kw = 0; kw < 3; ++kw) {
                int cc = 2*opx_l + kw;   // 0..14
                ushort4 u = patch[(kh*16 + cc)*32 + (g ^ cc)];
                float4 wv = w[kh*3 + kw];
                acc = fmaf(bf2f(u.x), wv.x, acc);
                acc = fmaf(bf2f(u.y), wv.y, acc);
                acc = fmaf(bf2f(u.z), wv.z, acc);
                acc = fmaf(bf2f(u.w), wv.w, acc);
            }
        }
        int opx = row*28 + q*7 + opx_l;
        V[(size_t)opx*128 + k] = fmaxf(acc + t3, 0.f);
    }
}

// Stage 2b: 1x1 conv (GEMM) + bsum + residual. Block = 8 opx, 256 thr, grid 1568.
__global__ __launch_bounds__(256)
void stage2b_kernel(const float* __restrict__ x,
                    const float* __restrict__ W2,     // [128,256]
                    const float* __restrict__ tabs,   // ws
                    const float* __restrict__ V,      // ws + OFF_V
                    float* __restrict__ out) {
    __shared__ float vs[8*128];
    __shared__ float res_s[8];
    int tid = threadIdx.x;
    int opxBase = blockIdx.x * 8;

    // stage V rows (coalesced)
    {
        const float* Vb = V + (size_t)opxBase * 128;
        #pragma unroll
        for (int jj = 0; jj < 4; ++jj) vs[tid + 256*jj] = Vb[tid + 256*jj];
    }
    // residual: res[p] = sum_c x[b, 2oh, 2ow, c]
    {
        int p = tid >> 5, l = tid & 31;
        int opx = opxBase + p;
        int b = opx / 784, r = opx - b*784;
        int oh = r / 28, ow = r - oh*28;
        const float* xp = x + (size_t)((b*56 + 2*oh)*56 + 2*ow) * 128;
        float rv = xp[l] + xp[l+32] + xp[l+64] + xp[l+96];
        #pragma unroll
        for (int off = 16; off; off >>= 1) rv += __shfl_down(rv, off, 32);
        if (l == 0) res_s[p] = rv;
    }
    __syncthreads();

    // out[opx][co] = vs @ W2 + bsum + res, thread = co
    int co = tid;
    float acc[8];
    {
        float bs = tabs[OFF_BSUM + co];
        #pragma unroll
        for (int p = 0; p < 8; ++p) acc[p] = bs;
    }
    const float* W2c = W2 + co;
    #pragma unroll 4
    for (int k4 = 0; k4 < 32; ++k4) {
        float w0 = W2c[(4*k4+0)*256];
        float w1 = W2c[(4*k4+1)*256];
        float w2 = W2c[(4*k4+2)*256];
        float w3 = W2c[(4*k4+3)*256];
        #pragma unroll
        for (int p = 0; p < 8; ++p) {
            float4 v = *(const float4*)&vs[p*128 + k4*4];   // broadcast
            acc[p] = fmaf(v.x, w0, acc[p]);
            acc[p] = fmaf(v.y, w1, acc[p]);
            acc[p] = fmaf(v.z, w2, acc[p]);
            acc[p] = fmaf(v.w, w3, acc[p]);
        }
    }
    #pragma unroll
    for (int p = 0; p < 8; ++p)
        out[(size_t)(opxBase + p)*256 + co] = acc[p] + res_s[p];
}

extern "C" void kernel_launch(void* const* d_in, const int* in_sizes, int n_in,
                              void* d_out, int out_size, void* d_ws, size_t ws_size,
                              hipStream_t stream) {
    const float* x   = (const float*)d_in[0];
    const float* g1  = (const float*)d_in[1];
    const float* be1 = (const float*)d_in[2];
    const float* m1  = (const float*)d_in[3];
    const float* v1  = (const float*)d_in[4];
    const float* W1  = (const float*)d_in[5];
    const float* b1  = (const float*)d_in[6];
    const float* g2  = (const float*)d_in[7];
    const float* be2 = (const float*)d_in[8];
    const float* m2  = (const float*)d_in[9];
    const float* v2  = (const float*)d_in[10];
    const float* W3  = (const float*)d_in[11];
    const float* b3  = (const float*)d_in[12];
    const float* g3  = (const float*)d_in[13];
    const float* be3 = (const float*)d_in[14];
    const float* m3  = (const float*)d_in[15];
    const float* v3  = (const float*)d_in[16];
    const float* W2  = (const float*)d_in[17];
    const float* b2  = (const float*)d_in[18];
    float* out = (float*)d_out;
    float* ws  = (float*)d_ws;

    prep_kernel<<<32, 256, 0, stream>>>(g1, be1, m1, v1, W1, b1, g2, be2, m2,
                                        v2, W3, b3, g3, be3, m3, v3, b2, ws);
    stage1_kernel<<<NPIX / 64, 256, 0, stream>>>(x, ws, ws + OFF_U);
    stage2a_kernel<<<448 * 4, 256, 0, stream>>>(ws, ws + OFF_U, ws + OFF_V);
    stage2b_kernel<<<NOPIX / 8, 256, 0, stream>>>(x, W2, ws, ws + OFF_V, out);
}

// Round 4
// 178.025 us; speedup vs baseline: 1.1074x; 1.1074x over previous
//
#include <hip/hip_runtime.h>
#include <hip/hip_bf16.h>

#define EPS 1e-3f
#define NPIX  50176   // 16*56*56
#define NOPIX 12544   // 16*28*28

// ws float offsets
#define OFF_S2   0        // [32][4]  s2
#define OFF_T2   128      // [32][4]  t2
#define OFF_T3   256      // [128]
#define OFF_BSUM 384      // [256]
#define OFF_W3S  640      // [128 k][36 = 9kk x 4ci] pre-scaled by s3
#define OFF_T3P  5248     // [32 g][128 c]  t' = bn1 shift in relu(x+t') form
#define OFF_WAF  9344     // A-frag table: [32 g][4 kk][64 lane][8 bf16] (32768 floats)
#define OFF_U    42112    // [32 g][50176 px] ushort4 (bf16, g-planar)
#define OFF_V    3253376  // [12544 opx][128 k] f32 conv3 output (post BN3+ReLU)

typedef __attribute__((ext_vector_type(8))) short short8v;
typedef __attribute__((ext_vector_type(4))) float f32x4;

__device__ __forceinline__ unsigned short f2bf(float f) {
    unsigned u = __float_as_uint(f);
    return (unsigned short)((u + 0x7fffu + ((u >> 16) & 1u)) >> 16);
}
__device__ __forceinline__ float bf2f(unsigned short s) {
    return __uint_as_float(((unsigned)s) << 16);
}
__device__ __forceinline__ unsigned pk2bf(float lo, float hi) {
    __hip_bfloat162 p = __float22bfloat162_rn(make_float2(lo, hi)); // RNE, lo in bits[15:0]
    union { __hip_bfloat162 h; unsigned u; } c; c.h = p;
    return c.u;
}

__global__ __launch_bounds__(256)
void prep_kernel(const float* __restrict__ g1, const float* __restrict__ be1,
                 const float* __restrict__ m1, const float* __restrict__ v1,
                 const float* __restrict__ W1, const float* __restrict__ b1,
                 const float* __restrict__ g2, const float* __restrict__ be2,
                 const float* __restrict__ m2, const float* __restrict__ v2,
                 const float* __restrict__ W3, const float* __restrict__ b3,
                 const float* __restrict__ g3, const float* __restrict__ be3,
                 const float* __restrict__ m3, const float* __restrict__ v3,
                 const float* __restrict__ b2, float* __restrict__ ws) {
    int gid = blockIdx.x * 256 + threadIdx.x;
    int stride = gridDim.x * 256;
    // t' table [g][c]: relu(bn1(x)) = s1 * relu(x + t'), t' = be1/s1 - m1
    for (int i = gid; i < 4096; i += stride) {
        float s = g1[i] * rsqrtf(v1[i] + EPS);
        ws[OFF_T3P + i] = be1[i] / s - m1[i];
    }
    // W' A-fragment table (bf16): lane l holds A[m=l&15][k=(l>>4)*8+j], m=f (<4), k=c within kk-slice
    {
        unsigned short* wsu = (unsigned short*)(ws + OFF_WAF);
        for (int i = gid; i < 65536; i += stride) {
            int j    = i & 7;
            int lane = (i >> 3) & 63;
            int kk   = (i >> 9) & 3;
            int g    = i >> 11;
            int f    = lane & 15;
            int c    = kk*32 + (lane >> 4)*8 + j;
            unsigned short v = 0;
            if (f < 4) {
                float s = g1[g*128 + c] * rsqrtf(v1[g*128 + c] + EPS);
                v = f2bf(s * W1[g*512 + c*4 + f]);
            }
            wsu[i] = v;
        }
    }
    // W3 re-laid [k][kk*4+ci], pre-scaled by s3  (k = g*4+f)
    for (int i = gid; i < 4608; i += stride) {
        int k = i / 36, j = i - k*36;
        int kk = j >> 2, ci = j & 3;
        int g = k >> 2, f = k & 3;
        float s3 = g3[k] * rsqrtf(v3[k] + EPS);
        ws[OFF_W3S + i] = W3[g*144 + kk*16 + ci*4 + f] * s3;
    }
    if (gid < 128) {
        float s2 = g2[gid] * rsqrtf(v2[gid] + EPS);
        ws[OFF_S2 + gid] = s2;
        ws[OFF_T2 + gid] = be2[gid] + (b1[gid] - m2[gid]) * s2;
        float s3 = g3[gid] * rsqrtf(v3[gid] + EPS);
        ws[OFF_T3 + gid] = be3[gid] + (b3[gid] - m3[gid]) * s3;
    } else if (gid >= 256 && gid < 512) {
        int co = gid - 256;
        float acc = 0.f;
        for (int g = 0; g < 32; ++g) acc += b2[g*256 + co];
        ws[OFF_BSUM + co] = acc;
    }
}

// Stage 1 (MFMA): grid = 784 64-px tiles x 2 g-halves; block 256 = 4 waves.
// Wave owns 4 groups x 64 px. A-fragments hoisted to VGPRs (t-invariant),
// t' broadcast-read from LDS, z-compute in packed f32.
__global__ __launch_bounds__(256)
void stage1_kernel(const float* __restrict__ x,
                   const float* __restrict__ tabs,   // ws
                   float* __restrict__ uout) {       // ws + OFF_U
    __shared__ float4 xs4[2048];   // 32 KB: 64 px x 32 float4, XOR-swizzled
    __shared__ float tps[2048];    // 8 KB: [16 g][128 c] t'
    int tid = threadIdx.x;
    int tile  = blockIdx.x >> 1;
    int ghalf = blockIdx.x & 1;

    const float4* xg = (const float4*)x + (size_t)tile * 2048;
    for (int i = tid; i < 2048; i += 256) {
        int p = i >> 5, c4 = i & 31;
        xs4[p*32 + (c4 ^ (p & 31))] = xg[i];
    }
    {
        const float4* tsrc = (const float4*)(tabs + OFF_T3P) + ghalf*512;
        float4* tdst = (float4*)tps;
        #pragma unroll
        for (int r = 0; r < 2; ++r) tdst[tid + 256*r] = tsrc[tid + 256*r];
    }
    __syncthreads();

    int lane = tid & 63;
    int wid  = tid >> 6;
    int g0 = __builtin_amdgcn_readfirstlane(ghalf*16 + wid*4);
    int l15 = lane & 15;
    int lq  = lane >> 4;           // k-chunk: k = lq*8 + j

    const uint4* wafp = (const uint4*)(tabs + OFF_WAF);
    uint2* Uo = (uint2*)uout;

    // hoist A-fragments (t-invariant): [gi][kk], statically indexed below
    union { uint4 u; short8v s; } af[4][4];
    #pragma unroll
    for (int gi = 0; gi < 4; ++gi)
        #pragma unroll
        for (int kk = 0; kk < 4; ++kk)
            af[gi][kk].u = wafp[((g0 + gi)*4 + kk)*64 + lane];

    const f32x4 zro = {0.f, 0.f, 0.f, 0.f};

    #pragma unroll 1
    for (int t = 0; t < 4; ++t) {
        int pxl = t*16 + l15;      // B-frag: n = px = l15
        f32x4 xf[8];
        #pragma unroll
        for (int kk = 0; kk < 4; ++kk) {
            xf[kk*2]   = *(const f32x4*)&xs4[pxl*32 + ((kk*8 + lq*2    ) ^ (pxl & 31))];
            xf[kk*2+1] = *(const f32x4*)&xs4[pxl*32 + ((kk*8 + lq*2 + 1) ^ (pxl & 31))];
        }
        #pragma unroll
        for (int gi = 0; gi < 4; ++gi) {
            int g = g0 + gi;
            int gl = wid*4 + gi;
            f32x4 acc = zro;
            #pragma unroll
            for (int kk = 0; kk < 4; ++kk) {
                const f32x4* tp = (const f32x4*)&tps[gl*128 + kk*32 + lq*8];
                f32x4 za = xf[kk*2]   + tp[0];
                f32x4 zb = xf[kk*2+1] + tp[1];
                za = __builtin_elementwise_max(za, zro);
                zb = __builtin_elementwise_max(zb, zro);
                union { unsigned u[4]; short8v s; } zz;
                zz.u[0] = pk2bf(za[0], za[1]);
                zz.u[1] = pk2bf(za[2], za[3]);
                zz.u[2] = pk2bf(zb[0], zb[1]);
                zz.u[3] = pk2bf(zb[2], zb[3]);
                acc = __builtin_amdgcn_mfma_f32_16x16x32_bf16(af[gi][kk].s, zz.s, acc, 0, 0, 0);
            }
            // epilogue: lane<16 holds px=pxl's f0..3 in acc[0..3]
            const float4 s2v = ((const float4*)(tabs + OFF_S2))[g];
            const float4 t2v = ((const float4*)(tabs + OFF_T2))[g];
            float o0 = fmaxf(fmaf(acc[0], s2v.x, t2v.x), 0.f);
            float o1 = fmaxf(fmaf(acc[1], s2v.y, t2v.y), 0.f);
            float o2 = fmaxf(fmaf(acc[2], s2v.z, t2v.z), 0.f);
            float o3 = fmaxf(fmaf(acc[3], s2v.w, t2v.w), 0.f);
            uint2 val;
            val.x = pk2bf(o0, o1);
            val.y = pk2bf(o2, o3);
            if (lane < 16)
                Uo[(size_t)g * NPIX + tile*64 + t*16 + lane] = val;
        }
    }
}

// Stage 2a: 3x3 stride-2 conv. Block = quarter-row (7 opx), 256 thr, grid 1792.
__global__ __launch_bounds__(256)
void stage2a_kernel(const float* __restrict__ tabs,   // ws
                    const float* __restrict__ U,      // ws + OFF_U (bf16)
                    float* __restrict__ V) {          // ws + OFF_V
    __shared__ ushort4 patch[3*16*32];   // [r][c][g ^ c]   12288 B

    int tid = threadIdx.x;
    int row = blockIdx.x >> 2;           // b*28 + oh
    int q   = blockIdx.x & 3;            // quarter: opx = q*7 .. q*7+6
    int b = row / 28, oh = row - b*28;

    // ---- stage U patch: rows ih = 2oh-1..2oh+1, cols ic = 14q-1 .. 14q+13 ----
    {
        const ushort4* Uu = (const ushort4*)U;
        #pragma unroll 1
        for (int i = tid; i < 1440; i += 256) {
            int g = i / 45;
            int rem = i - g*45;
            int r = rem / 15;            // 0..2
            int c = rem - r*15;          // 0..14
            int ih = 2*oh - 1 + r;
            int ic = 14*q - 1 + c;
            ushort4 v = make_ushort4(0, 0, 0, 0);
            if (ih >= 0 && ic >= 0)
                v = Uu[(size_t)g * NPIX + (b*56 + ih)*56 + ic];
            patch[(r*16 + c)*32 + (g ^ c)] = v;
        }
    }

    // weights into VGPRs: 9 float4 per thread (L2-hot table)
    int k = tid & 127, s = tid >> 7;     // s in {0,1}
    int g = k >> 2;
    float4 w[9];
    {
        const float4* wk = (const float4*)(tabs + OFF_W3S + k*36);
        #pragma unroll
        for (int kk = 0; kk < 9; ++kk) w[kk] = wk[kk];
    }
    float t3 = tabs[OFF_T3 + k];
    __syncthreads();

    // ---- conv: opx_l = s + 2j (parity split), each ushort4 read broadcast x4 f ----
    #pragma unroll
    for (int j = 0; j < 4; ++j) {
        int opx_l = s + 2*j;
        if (opx_l > 6) break;
        float acc = 0.f;
        #pragma unroll
        for (int kh = 0; kh < 3; ++kh) {
            #pragma unroll
            for (int kw = 0; kw < 3; ++kw) {
                int cc = 2*opx_l + kw;   // 0..14
                ushort4 u = patch[(kh*16 + cc)*32 + (g ^ cc)];
                float4 wv = w[kh*3 + kw];
                acc = fmaf(bf2f(u.x), wv.x, acc);
                acc = fmaf(bf2f(u.y), wv.y, acc);
                acc = fmaf(bf2f(u.z), wv.z, acc);
                acc = fmaf(bf2f(u.w), wv.w, acc);
            }
        }
        int opx = row*28 + q*7 + opx_l;
        V[(size_t)opx*128 + k] = fmaxf(acc + t3, 0.f);
    }
}

// Stage 2b: 1x1 conv (GEMM) + bsum + residual. Block = 8 opx, 256 thr, grid 1568.
__global__ __launch_bounds__(256)
void stage2b_kernel(const float* __restrict__ x,
                    const float* __restrict__ W2,     // [128,256]
                    const float* __restrict__ tabs,   // ws
                    const float* __restrict__ V,      // ws + OFF_V
                    float* __restrict__ out) {
    __shared__ float vs[8*128];
    __shared__ float res_s[8];
    int tid = threadIdx.x;
    int opxBase = blockIdx.x * 8;

    // stage V rows (coalesced)
    {
        const float* Vb = V + (size_t)opxBase * 128;
        #pragma unroll
        for (int jj = 0; jj < 4; ++jj) vs[tid + 256*jj] = Vb[tid + 256*jj];
    }
    // residual: res[p] = sum_c x[b, 2oh, 2ow, c]
    {
        int p = tid >> 5, l = tid & 31;
        int opx = opxBase + p;
        int b = opx / 784, r = opx - b*784;
        int oh = r / 28, ow = r - oh*28;
        const float* xp = x + (size_t)((b*56 + 2*oh)*56 + 2*ow) * 128;
        float rv = xp[l] + xp[l+32] + xp[l+64] + xp[l+96];
        #pragma unroll
        for (int off = 16; off; off >>= 1) rv += __shfl_down(rv, off, 32);
        if (l == 0) res_s[p] = rv;
    }
    __syncthreads();

    // out[opx][co] = vs @ W2 + bsum + res, thread = co
    int co = tid;
    float acc[8];
    {
        float bs = tabs[OFF_BSUM + co];
        #pragma unroll
        for (int p = 0; p < 8; ++p) acc[p] = bs;
    }
    const float* W2c = W2 + co;
    #pragma unroll 4
    for (int k4 = 0; k4 < 32; ++k4) {
        float w0 = W2c[(4*k4+0)*256];
        float w1 = W2c[(4*k4+1)*256];
        float w2 = W2c[(4*k4+2)*256];
        float w3 = W2c[(4*k4+3)*256];
        #pragma unroll
        for (int p = 0; p < 8; ++p) {
            float4 v = *(const float4*)&vs[p*128 + k4*4];   // broadcast
            acc[p] = fmaf(v.x, w0, acc[p]);
            acc[p] = fmaf(v.y, w1, acc[p]);
            acc[p] = fmaf(v.z, w2, acc[p]);
            acc[p] = fmaf(v.w, w3, acc[p]);
        }
    }
    #pragma unroll
    for (int p = 0; p < 8; ++p)
        out[(size_t)(opxBase + p)*256 + co] = acc[p] + res_s[p];
}

extern "C" void kernel_launch(void* const* d_in, const int* in_sizes, int n_in,
                              void* d_out, int out_size, void* d_ws, size_t ws_size,
                              hipStream_t stream) {
    const float* x   = (const float*)d_in[0];
    const float* g1  = (const float*)d_in[1];
    const float* be1 = (const float*)d_in[2];
    const float* m1  = (const float*)d_in[3];
    const float* v1  = (const float*)d_in[4];
    const float* W1  = (const float*)d_in[5];
    const float* b1  = (const float*)d_in[6];
    const float* g2  = (const float*)d_in[7];
    const float* be2 = (const float*)d_in[8];
    const float* m2  = (const float*)d_in[9];
    const float* v2  = (const float*)d_in[10];
    const float* W3  = (const float*)d_in[11];
    const float* b3  = (const float*)d_in[12];
    const float* g3  = (const float*)d_in[13];
    const float* be3 = (const float*)d_in[14];
    const float* m3  = (const float*)d_in[15];
    const float* v3  = (const float*)d_in[16];
    const float* W2  = (const float*)d_in[17];
    const float* b2  = (const float*)d_in[18];
    float* out = (float*)d_out;
    float* ws  = (float*)d_ws;

    prep_kernel<<<32, 256, 0, stream>>>(g1, be1, m1, v1, W1, b1, g2, be2, m2,
                                        v2, W3, b3, g3, be3, m3, v3, b2, ws);
    stage1_kernel<<<(NPIX / 64) * 2, 256, 0, stream>>>(x, ws, ws + OFF_U);
    stage2a_kernel<<<448 * 4, 256, 0, stream>>>(ws, ws + OFF_U, ws + OFF_V);
    stage2b_kernel<<<NOPIX / 8, 256, 0, stream>>>(x, W2, ws, ws + OFF_V, out);
}